// Round 1
// baseline (681.970 us; speedup 1.0000x reference)
//
#include <hip/hip_runtime.h>
#include <math.h>

// Problem constants
constexpr int kB    = 64;
constexpr int kN    = 32;
constexpr int kDIN  = 128;
constexpr int kH    = 256;
constexpr int kG4   = 1024;   // 4*H
constexpr int kDOUT = 128;
constexpr int kBN   = 2048;   // B*N

typedef __attribute__((ext_vector_type(8))) short bf16x8;
typedef __attribute__((ext_vector_type(4))) float f32x4;

// fast sigmoid/tanh: v_exp_f32 + v_rcp_f32 (1-2 ulp, far below bf16-h noise)
__device__ __forceinline__ float sigm(float x) {
    return __builtin_amdgcn_rcpf(1.0f + __expf(-x));
}
__device__ __forceinline__ float tanh_f(float x) {
    // tanh(x) = 1 - 2/(1+e^{2x}); saturates correctly at +-inf
    return 1.0f - 2.0f * __builtin_amdgcn_rcpf(1.0f + __expf(2.0f * x));
}

// fp32 -> bf16 bits, round-to-nearest-even
__device__ __forceinline__ short f2bf(float f) {
    union { float f; unsigned u; } v; v.f = f;
    unsigned r = v.u + 0x7fffu + ((v.u >> 16) & 1u);
    return (short)(r >> 16);
}

// ---------------------------------------------------------------------------
// prep:
//   [0,128)   transpose W_ih_f (1024x128) -> WihT_f [k][gate]
//   [128,256) transpose W_ih_r            -> WihT_r
//   [256,320) transpose W_fc   (128x512)  -> WfcT   [k][dout]
//   [320,448) pack W_hh (bf16) into per-wave MFMA fragment order:
//             Wp[((w*8+kt)*8+tau)*512 + lane*8 + j]
//               = W_hh[nb(w,tau)+l15][kt*32+quad*8+j]
//             -> each (kt,tau) fragment load is 1KiB wave-contiguous.
//   [448,456) transpose mask -> mask_t [n][t][b]
// ---------------------------------------------------------------------------
__global__ __launch_bounds__(256) void prep_k(
    const float* __restrict__ Wihf, const float* __restrict__ Wihr,
    const float* __restrict__ Whhf, const float* __restrict__ Whhr,
    const float* __restrict__ Wfc,  const float* __restrict__ mask,
    float* __restrict__ WihTf, float* __restrict__ WihTr,
    float* __restrict__ WfcT,  float* __restrict__ mask_t,
    short* __restrict__ Wp_f,  short* __restrict__ Wp_r)
{
    const int bx  = blockIdx.x;
    const int tid = threadIdx.y * 32 + threadIdx.x;

    if (bx >= 448) {                       // mask transpose: [b][n][t] -> [n][t][b]
        const int base = (bx - 448) * 8192 + tid;
        #pragma unroll
        for (int i = 0; i < 32; ++i) {
            const int idx = base + i * 256;
            const int n = idx >> 11, tt = (idx >> 6) & 31, b = idx & 63;
            mask_t[idx] = mask[(size_t)b * 1024 + n * 32 + tt];
        }
        return;
    }
    if (bx >= 320) {                       // W_hh fragment pack
        const int idx = bx - 320;
        const int dir = idx >> 6;
        const int wv  = (idx >> 3) & 7;
        const int kt  = idx & 7;
        const float* src = dir ? Whhr : Whhf;
        short* dst = (dir ? Wp_r : Wp_f) + (size_t)((wv * 8 + kt) * 8) * 512;
        for (int i = tid; i < 512; i += 256) {
            const int tau = i >> 6, lane = i & 63;
            const int qd = lane >> 4, l = lane & 15;
            const int gate = (tau >> 1) * 256 + wv * 32 + (tau & 1) * 16 + l;
            const int ks = kt * 32 + qd * 8;
            bf16x8 v;
            #pragma unroll
            for (int j = 0; j < 8; ++j) v[j] = f2bf(src[(size_t)gate * kH + ks + j]);
            *(bf16x8*)(dst + tau * 512 + lane * 8) = v;
        }
        return;
    }
    __shared__ float tile[32][33];
    const float* src; float* dst; int R, C, t;
    if (bx < 128)      { src = Wihf; dst = WihTf; R = 1024; C = 128; t = bx; }
    else if (bx < 256) { src = Wihr; dst = WihTr; R = 1024; C = 128; t = bx - 128; }
    else               { src = Wfc;  dst = WfcT;  R = 128;  C = 512; t = bx - 256; }
    const int tilesX = C / 32;
    const int c0 = (t % tilesX) * 32;
    const int r0 = (t / tilesX) * 32;
    const int tx = threadIdx.x, ty = threadIdx.y;
    #pragma unroll
    for (int i = ty; i < 32; i += 8)
        tile[i][tx] = src[(size_t)(r0 + i) * C + (c0 + tx)];
    __syncthreads();
    #pragma unroll
    for (int i = ty; i < 32; i += 8)
        dst[(size_t)(c0 + i) * R + (r0 + tx)] = tile[tx][i];
}

// ---------------------------------------------------------------------------
// k1: xW = x @ W_ih.T, written directly in k2's packed-fragment layout:
//   xWP[(t*2+bh)*8192 + w*1024 + tau*128 + Mt*64 + quad*16 + l15] (float4 over r)
//     = xW(b = bh*32+Mt*16+quad*4+r, gate = nb(w,tau)+l15)
// Grid 256 = dir(2) x t(32) x bq(4: 16 b's). 256 thr; thread = 8 rows x 8 gates
// register tile (VALU-bound, ~balanced LDS), W streamed coalesced from WihT.
// ---------------------------------------------------------------------------
__global__ __launch_bounds__(256) void k1_xw(
    const float* __restrict__ x,
    const float* __restrict__ WihT_f, const float* __restrict__ WihT_r,
    float* __restrict__ xWP_f, float* __restrict__ xWP_r)
{
    __shared__ float xs[16][128];
    const int tid  = threadIdx.x;
    const int bx   = blockIdx.x;
    const int dir  = bx >> 7;
    const int rest = bx & 127;
    const int t    = rest >> 2;
    const int bq   = rest & 3;
    const float* __restrict__ WT = dir ? WihT_r : WihT_f;
    float* __restrict__ xWP = dir ? xWP_r : xWP_f;

    for (int i = tid; i < 512; i += 256) {
        const int rr = i >> 5, c4 = i & 31;
        *(f32x4*)&xs[rr][c4 * 4] =
            *(const f32x4*)&x[((size_t)(bq * 16 + rr) * 32 + t) * 128 + c4 * 4];
    }
    __syncthreads();

    const int rowg = tid >> 7;    // 0..1 -> rows rowg*8..+7
    const int gg   = tid & 127;   // gates {gg*4+j} and {512+gg*4+j}

    float acc0[8][4], acc1[8][4];
    #pragma unroll
    for (int r = 0; r < 8; ++r)
        #pragma unroll
        for (int j = 0; j < 4; ++j) { acc0[r][j] = 0.f; acc1[r][j] = 0.f; }

    for (int k4 = 0; k4 < 32; ++k4) {
        f32x4 w0[4], w1[4], xv[8];
        #pragma unroll
        for (int kk = 0; kk < 4; ++kk) {
            w0[kk] = *(const f32x4*)&WT[(size_t)(k4 * 4 + kk) * 1024 + gg * 4];
            w1[kk] = *(const f32x4*)&WT[(size_t)(k4 * 4 + kk) * 1024 + 512 + gg * 4];
        }
        #pragma unroll
        for (int r = 0; r < 8; ++r) xv[r] = *(const f32x4*)&xs[rowg * 8 + r][k4 * 4];
        #pragma unroll
        for (int r = 0; r < 8; ++r)
            #pragma unroll
            for (int kk = 0; kk < 4; ++kk) {
                const float xk = xv[r][kk];
                #pragma unroll
                for (int j = 0; j < 4; ++j) {
                    acc0[r][j] = fmaf(xk, w0[kk][j], acc0[r][j]);
                    acc1[r][j] = fmaf(xk, w1[kk][j], acc1[r][j]);
                }
            }
    }

    const int b0 = bq * 16 + rowg * 8;
    #pragma unroll
    for (int hf = 0; hf < 2; ++hf)
        #pragma unroll
        for (int j = 0; j < 4; ++j) {
            const int g    = hf * 512 + gg * 4 + j;
            const int l15g = g & 15;
            const int qg   = (g >> 4) & 1;
            const int wg   = (g >> 5) & 7;
            const int taug = (g >> 8) * 2 + qg;
            #pragma unroll
            for (int p = 0; p < 2; ++p) {
                const int b  = b0 + p * 4;
                const int bh = b >> 5, Mt = (b >> 4) & 1, qd = (b >> 2) & 3;
                f32x4 v;
                #pragma unroll
                for (int r = 0; r < 4; ++r)
                    v[r] = hf ? acc1[p * 4 + r][j] : acc0[p * 4 + r][j];
                ((f32x4*)xWP)[(size_t)(t * 2 + bh) * 8192 + wg * 1024 + taug * 128
                              + Mt * 64 + qd * 16 + l15g] = v;
            }
        }
}

// ---------------------------------------------------------------------------
// k2: bidirectional LSTM recurrence, bf16 MFMA fp32 accumulate.
// Grid 128 = dir(2) x n(32) x bh(2: 32 batches). 512 thr = 8 waves.
// M=32 (2 MFMA row-tiles) -> every W fragment feeds 2x the MFMA work.
// W streamed from packed per-wave-contiguous layout (8 segs/load, L2-resident);
// kt=0,1 persisted in 64 VGPRs. mask*xW (packed, wave-contiguous float4 loads)
// issued at step start, injected into acc after kt==2 (commutes with MFMA
// accumulation) so L2/L3 latency hides under ~3 kt of MFMAs.
// K-loop skipped at it==0 (h=0) -> no LDS zero-init needed.
// ---------------------------------------------------------------------------
__global__ __launch_bounds__(512, 2) void k2_lstm(
    const float* __restrict__ mask_t,
    const float* __restrict__ xWP_f, const float* __restrict__ xWP_r,
    const short* __restrict__ Wp_f, const short* __restrict__ Wp_r,
    const float* __restrict__ b_f,  const float* __restrict__ b_r,
    float* __restrict__ y)
{
    constexpr int HP = 272;
    __shared__ short h_lds[2][32][HP];          // 34.8 KB

    const int tid  = threadIdx.x;
    const int w    = tid >> 6;
    const int lane = tid & 63;
    const int quad = lane >> 4;
    const int l15  = lane & 15;

    const int bx    = blockIdx.x;
    const int dir   = bx >> 6;                  // 0 fwd, 1 rev
    const int rest  = bx & 63;
    const int n_seq = rest >> 1;                // 0..31
    const int bh    = rest & 1;                 // batch half (32 each)

    const float* __restrict__ xWP = dir ? xWP_r : xWP_f;
    const short* __restrict__ Wp  = dir ? Wp_r  : Wp_f;
    const float* __restrict__ bb  = dir ? b_r   : b_f;

    float bias[8];
    #pragma unroll
    for (int g = 0; g < 4; ++g)
        #pragma unroll
        for (int q = 0; q < 2; ++q)
            bias[g * 2 + q] = bb[g * 256 + w * 32 + q * 16 + l15];

    const short* wbase = Wp + (size_t)w * 8 * 8 * 512 + lane * 8;

    bf16x8 wreg[8][2];                          // kt = 0,1 persisted
    #pragma unroll
    for (int tau = 0; tau < 8; ++tau)
        #pragma unroll
        for (int k2i = 0; k2i < 2; ++k2i)
            wreg[tau][k2i] = *(const bf16x8*)(wbase + (k2i * 8 + tau) * 512);

    float c[16];
    #pragma unroll
    for (int i = 0; i < 16; ++i) c[i] = 0.f;

    const int nsteps = dir ? (kN - n_seq) : (n_seq + 1);

    int cur = 0;
    for (int it = 0; it < nsteps; ++it) {
        const int t = dir ? (kN - 1 - it) : it;

        // issue this step's packed xW + mask loads (consumed after kt==2)
        const f32x4* xb4 = (const f32x4*)xWP
            + ((size_t)(t * 2 + bh) * 8192 + w * 1024 + lane);
        f32x4 xv[8][2];
        #pragma unroll
        for (int tau = 0; tau < 8; ++tau)
            #pragma unroll
            for (int Mt = 0; Mt < 2; ++Mt)
                xv[tau][Mt] = xb4[tau * 128 + Mt * 64];
        f32x4 mkv[2];
        #pragma unroll
        for (int Mt = 0; Mt < 2; ++Mt)
            mkv[Mt] = ((const f32x4*)mask_t)[(n_seq * 32 + t) * 16 + bh * 8 + Mt * 4 + quad];

        f32x4 acc[8][2];
        #pragma unroll
        for (int tau = 0; tau < 8; ++tau) {
            const f32x4 bv = {bias[tau], bias[tau], bias[tau], bias[tau]};
            acc[tau][0] = bv; acc[tau][1] = bv;
        }

        if (it > 0) {
            #pragma unroll
            for (int kt = 0; kt < 8; ++kt) {
                const bf16x8 a0 = *(const bf16x8*)&h_lds[cur][l15][kt * 32 + quad * 8];
                const bf16x8 a1 = *(const bf16x8*)&h_lds[cur][16 + l15][kt * 32 + quad * 8];
                #pragma unroll
                for (int tau = 0; tau < 8; ++tau) {
                    const bf16x8 bfr = (kt < 2) ? wreg[tau][kt]
                        : *(const bf16x8*)(wbase + (kt * 8 + tau) * 512);
                    acc[tau][0] = __builtin_amdgcn_mfma_f32_16x16x32_bf16(a0, bfr, acc[tau][0], 0, 0, 0);
                    acc[tau][1] = __builtin_amdgcn_mfma_f32_16x16x32_bf16(a1, bfr, acc[tau][1], 0, 0, 0);
                }
                if (kt == 2) {
                    #pragma unroll
                    for (int tau = 0; tau < 8; ++tau)
                        #pragma unroll
                        for (int Mt = 0; Mt < 2; ++Mt)
                            #pragma unroll
                            for (int r = 0; r < 4; ++r)
                                acc[tau][Mt][r] = fmaf(mkv[Mt][r], xv[tau][Mt][r], acc[tau][Mt][r]);
                }
            }
        } else {
            #pragma unroll
            for (int tau = 0; tau < 8; ++tau)
                #pragma unroll
                for (int Mt = 0; Mt < 2; ++Mt)
                    #pragma unroll
                    for (int r = 0; r < 4; ++r)
                        acc[tau][Mt][r] = fmaf(mkv[Mt][r], xv[tau][Mt][r], acc[tau][Mt][r]);
        }

        // epilogue: lane owns units u = w*32+q*16+l15, rows m = Mt*16+quad*4+r
        const int nxt = cur ^ 1;
        #pragma unroll
        for (int q = 0; q < 2; ++q)
            #pragma unroll
            for (int Mt = 0; Mt < 2; ++Mt)
                #pragma unroll
                for (int r = 0; r < 4; ++r) {
                    const int ci = (q * 2 + Mt) * 4 + r;
                    const float gI = acc[0 + q][Mt][r];
                    const float gF = acc[2 + q][Mt][r];
                    const float gG = acc[4 + q][Mt][r];
                    const float gO = acc[6 + q][Mt][r];
                    const float ct = sigm(gF) * c[ci] + sigm(gI) * tanh_f(gG);
                    c[ci] = ct;
                    const float hn = sigm(gO) * tanh_f(ct);
                    const int m = Mt * 16 + quad * 4 + r;
                    const int u = w * 32 + q * 16 + l15;
                    h_lds[nxt][m][u] = f2bf(hn);
                    if (t == n_seq)
                        y[((size_t)(bh * 32 + m) * kN + n_seq) * (2 * kH)
                          + dir * kH + u] = hn;
                }
        __syncthreads();
        cur = nxt;
    }
}

// ---------------------------------------------------------------------------
// k3: out = relu(y @ W_fc.T + b_fc). 128 blocks x 16 rows; 128 thr;
// thread = 4 rows x 4 cols register tile; W coalesced float4 from WfcT.
// ---------------------------------------------------------------------------
__global__ __launch_bounds__(128) void k3_out(
    const float* __restrict__ y, const float* __restrict__ WfcT,
    const float* __restrict__ b_fc, float* __restrict__ out)
{
    __shared__ float ys[16][512];               // 32 KB
    const int tid = threadIdx.x;
    const int r0  = blockIdx.x * 16;
    for (int i = tid; i < 2048; i += 128)
        ((f32x4*)ys)[i] = ((const f32x4*)(y + (size_t)r0 * 512))[i];
    __syncthreads();

    const int rowg = tid >> 5;                  // 0..3 -> rows rowg*4..+3
    const int cg   = tid & 31;                  // cols cg*4..+3

    f32x4 acc[4];
    #pragma unroll
    for (int r = 0; r < 4; ++r) acc[r] = (f32x4){0.f, 0.f, 0.f, 0.f};

    #pragma unroll 4
    for (int k = 0; k < 512; ++k) {
        const f32x4 wv = *(const f32x4*)&WfcT[(size_t)k * 128 + cg * 4];
        #pragma unroll
        for (int r = 0; r < 4; ++r) {
            const float yv = ys[rowg * 4 + r][k];
            #pragma unroll
            for (int j = 0; j < 4; ++j)
                acc[r][j] = fmaf(yv, wv[j], acc[r][j]);
        }
    }

    const f32x4 bv = *(const f32x4*)&b_fc[cg * 4];
    #pragma unroll
    for (int r = 0; r < 4; ++r) {
        f32x4 o;
        #pragma unroll
        for (int j = 0; j < 4; ++j) o[j] = fmaxf(acc[r][j] + bv[j], 0.f);
        *(f32x4*)&out[(size_t)(r0 + rowg * 4 + r) * 128 + cg * 4] = o;
    }
}

// ---------------------------------------------------------------------------
extern "C" void kernel_launch(void* const* d_in, const int* in_sizes, int n_in,
                              void* d_out, int out_size, void* d_ws, size_t ws_size,
                              hipStream_t stream) {
    const float* x      = (const float*)d_in[0];
    const float* mask   = (const float*)d_in[1];
    const float* W_ih_f = (const float*)d_in[2];
    const float* W_hh_f = (const float*)d_in[3];
    const float* b_f    = (const float*)d_in[4];
    const float* W_ih_r = (const float*)d_in[5];
    const float* W_hh_r = (const float*)d_in[6];
    const float* b_r    = (const float*)d_in[7];
    const float* W_fc   = (const float*)d_in[8];
    const float* b_fc   = (const float*)d_in[9];
    float* out = (float*)d_out;

    float* ws     = (float*)d_ws;
    float* WihT_f = ws;                        // 131072 f
    float* WihT_r = WihT_f + 131072;           // 131072 f
    float* WfcT   = WihT_r + 131072;           // 65536 f
    float* mask_t = WfcT + 65536;              // 65536 f
    float* xWP_f  = mask_t + 65536;            // 2097152 f
    float* xWP_r  = xWP_f + 2097152;           // 2097152 f
    float* yb     = xWP_r + 2097152;           // 1048576 f
    short* Wp_f   = (short*)(yb + 1048576);    // 262144 bf16
    short* Wp_r   = Wp_f + 262144;             // 262144 bf16

    prep_k<<<456, dim3(32, 8), 0, stream>>>(
        W_ih_f, W_ih_r, W_hh_f, W_hh_r, W_fc, mask,
        WihT_f, WihT_r, WfcT, mask_t, Wp_f, Wp_r);

    k1_xw<<<256, 256, 0, stream>>>(x, WihT_f, WihT_r, xWP_f, xWP_r);
    k2_lstm<<<128, 512, 0, stream>>>(mask_t, xWP_f, xWP_r, Wp_f, Wp_r, b_f, b_r, yb);
    k3_out<<<128, 128, 0, stream>>>(yb, WfcT, b_fc, out);
}

// Round 2
// 515.896 us; speedup vs baseline: 1.3219x; 1.3219x over previous
//
#include <hip/hip_runtime.h>
#include <math.h>

// Problem constants
constexpr int kB    = 64;
constexpr int kN    = 32;
constexpr int kDIN  = 128;
constexpr int kH    = 256;
constexpr int kG4   = 1024;   // 4*H
constexpr int kDOUT = 128;
constexpr int kBN   = 2048;   // B*N

typedef __attribute__((ext_vector_type(8))) short bf16x8;
typedef __attribute__((ext_vector_type(4))) float f32x4;

// fast sigmoid/tanh: v_exp_f32 + v_rcp_f32 (1-2 ulp, far below bf16-h noise)
__device__ __forceinline__ float sigm(float x) {
    return __builtin_amdgcn_rcpf(1.0f + __expf(-x));
}
__device__ __forceinline__ float tanh_f(float x) {
    return 1.0f - 2.0f * __builtin_amdgcn_rcpf(1.0f + __expf(2.0f * x));
}

// fp32 -> bf16 bits, round-to-nearest-even
__device__ __forceinline__ short f2bf(float f) {
    union { float f; unsigned u; } v; v.f = f;
    unsigned r = v.u + 0x7fffu + ((v.u >> 16) & 1u);
    return (short)(r >> 16);
}

// ---------------------------------------------------------------------------
// prep:
//   [0,128)   transpose W_ih_f (1024x128) -> WihT_f [k][gate]
//   [128,256) transpose W_ih_r            -> WihT_r
//   [256,320) transpose W_fc   (128x512)  -> WfcT   [k][dout]
//   [320,448) pack W_hh (bf16) into per-wave MFMA fragment order:
//             Wp[((w*8+kt)*8+tau)*512 + lane*8 + j]
//               = W_hh[nb(w,tau)+l15][kt*32+quad*8+j]
//   [448,456) transpose mask -> mask_t [n][t][b]
// ---------------------------------------------------------------------------
__global__ __launch_bounds__(256) void prep_k(
    const float* __restrict__ Wihf, const float* __restrict__ Wihr,
    const float* __restrict__ Whhf, const float* __restrict__ Whhr,
    const float* __restrict__ Wfc,  const float* __restrict__ mask,
    float* __restrict__ WihTf, float* __restrict__ WihTr,
    float* __restrict__ WfcT,  float* __restrict__ mask_t,
    short* __restrict__ Wp_f,  short* __restrict__ Wp_r)
{
    const int bx  = blockIdx.x;
    const int tid = threadIdx.y * 32 + threadIdx.x;

    if (bx >= 448) {                       // mask transpose: [b][n][t] -> [n][t][b]
        const int base = (bx - 448) * 8192 + tid;
        #pragma unroll
        for (int i = 0; i < 32; ++i) {
            const int idx = base + i * 256;
            const int n = idx >> 11, tt = (idx >> 6) & 31, b = idx & 63;
            mask_t[idx] = mask[(size_t)b * 1024 + n * 32 + tt];
        }
        return;
    }
    if (bx >= 320) {                       // W_hh fragment pack
        const int idx = bx - 320;
        const int dir = idx >> 6;
        const int wv  = (idx >> 3) & 7;
        const int kt  = idx & 7;
        const float* src = dir ? Whhr : Whhf;
        short* dst = (dir ? Wp_r : Wp_f) + (size_t)((wv * 8 + kt) * 8) * 512;
        for (int i = tid; i < 512; i += 256) {
            const int tau = i >> 6, lane = i & 63;
            const int qd = lane >> 4, l = lane & 15;
            const int gate = (tau >> 1) * 256 + wv * 32 + (tau & 1) * 16 + l;
            const int ks = kt * 32 + qd * 8;
            bf16x8 v;
            #pragma unroll
            for (int j = 0; j < 8; ++j) v[j] = f2bf(src[(size_t)gate * kH + ks + j]);
            *(bf16x8*)(dst + tau * 512 + lane * 8) = v;
        }
        return;
    }
    __shared__ float tile[32][33];
    const float* src; float* dst; int R, C, t;
    if (bx < 128)      { src = Wihf; dst = WihTf; R = 1024; C = 128; t = bx; }
    else if (bx < 256) { src = Wihr; dst = WihTr; R = 1024; C = 128; t = bx - 128; }
    else               { src = Wfc;  dst = WfcT;  R = 128;  C = 512; t = bx - 256; }
    const int tilesX = C / 32;
    const int c0 = (t % tilesX) * 32;
    const int r0 = (t / tilesX) * 32;
    const int tx = threadIdx.x, ty = threadIdx.y;
    #pragma unroll
    for (int i = ty; i < 32; i += 8)
        tile[i][tx] = src[(size_t)(r0 + i) * C + (c0 + tx)];
    __syncthreads();
    #pragma unroll
    for (int i = ty; i < 32; i += 8)
        dst[(size_t)(c0 + i) * R + (r0 + tx)] = tile[tx][i];
}

// ---------------------------------------------------------------------------
// k1: xW = x @ W_ih.T, written in k2's packed-fragment layout (M=16 tiles):
//   xWP[(t*4+bq)*4096 + w*512 + tau*64 + qd*16 + l15]  (f32x4 over r)
//     = xW(b = bq*16 + qd*4 + r, gate = nb(w,tau)+l15)
// Grid 256 = dir(2) x t(32) x bq(4). 256 thr; 8-row x 8-gate register tile.
// ---------------------------------------------------------------------------
__global__ __launch_bounds__(256) void k1_xw(
    const float* __restrict__ x,
    const float* __restrict__ WihT_f, const float* __restrict__ WihT_r,
    float* __restrict__ xWP_f, float* __restrict__ xWP_r)
{
    __shared__ float xs[16][128];
    const int tid  = threadIdx.x;
    const int bx   = blockIdx.x;
    const int dir  = bx >> 7;
    const int rest = bx & 127;
    const int t    = rest >> 2;
    const int bq   = rest & 3;
    const float* __restrict__ WT = dir ? WihT_r : WihT_f;
    float* __restrict__ xWP = dir ? xWP_r : xWP_f;

    for (int i = tid; i < 512; i += 256) {
        const int rr = i >> 5, c4 = i & 31;
        *(f32x4*)&xs[rr][c4 * 4] =
            *(const f32x4*)&x[((size_t)(bq * 16 + rr) * 32 + t) * 128 + c4 * 4];
    }
    __syncthreads();

    const int rowg = tid >> 7;    // 0..1 -> rows rowg*8..+7
    const int gg   = tid & 127;   // gates {gg*4+j} and {512+gg*4+j}

    float acc0[8][4], acc1[8][4];
    #pragma unroll
    for (int r = 0; r < 8; ++r)
        #pragma unroll
        for (int j = 0; j < 4; ++j) { acc0[r][j] = 0.f; acc1[r][j] = 0.f; }

    for (int k4 = 0; k4 < 32; ++k4) {
        f32x4 w0[4], w1[4], xv[8];
        #pragma unroll
        for (int kk = 0; kk < 4; ++kk) {
            w0[kk] = *(const f32x4*)&WT[(size_t)(k4 * 4 + kk) * 1024 + gg * 4];
            w1[kk] = *(const f32x4*)&WT[(size_t)(k4 * 4 + kk) * 1024 + 512 + gg * 4];
        }
        #pragma unroll
        for (int r = 0; r < 8; ++r) xv[r] = *(const f32x4*)&xs[rowg * 8 + r][k4 * 4];
        #pragma unroll
        for (int r = 0; r < 8; ++r)
            #pragma unroll
            for (int kk = 0; kk < 4; ++kk) {
                const float xk = xv[r][kk];
                #pragma unroll
                for (int j = 0; j < 4; ++j) {
                    acc0[r][j] = fmaf(xk, w0[kk][j], acc0[r][j]);
                    acc1[r][j] = fmaf(xk, w1[kk][j], acc1[r][j]);
                }
            }
    }

    #pragma unroll
    for (int hf = 0; hf < 2; ++hf)
        #pragma unroll
        for (int j = 0; j < 4; ++j) {
            const int g    = hf * 512 + gg * 4 + j;
            const int l15g = g & 15;
            const int qg   = (g >> 4) & 1;
            const int wg   = (g >> 5) & 7;
            const int taug = (g >> 8) * 2 + qg;
            #pragma unroll
            for (int p = 0; p < 2; ++p) {
                const int qd = rowg * 2 + p;          // m = qd*4 + r
                f32x4 v;
                #pragma unroll
                for (int r = 0; r < 4; ++r)
                    v[r] = hf ? acc1[p * 4 + r][j] : acc0[p * 4 + r][j];
                ((f32x4*)xWP)[(size_t)(t * 4 + bq) * 4096 + wg * 512 + taug * 64
                              + qd * 16 + l15g] = v;
            }
        }
}

// ---------------------------------------------------------------------------
// k2: bidirectional LSTM recurrence, bf16 MFMA fp32 accumulate.
// Grid 256 = dir(2) x n(32) x bq(4: 16 batches). 512 thr = 8 waves, M=16.
// W streamed from packed per-wave-contiguous layout (L2-resident, 8 segs/load).
// xW+mask for step t+1 prefetched into registers during step t (round-0's
// proven one-step-deep pipeline) from the packed layout (8 x f32x4 per wave).
// K-loop skipped at it==0 (h=0) -> no LDS zero-init.
// ---------------------------------------------------------------------------
__global__ __launch_bounds__(512, 2) void k2_lstm(
    const float* __restrict__ mask_t,
    const float* __restrict__ xWP_f, const float* __restrict__ xWP_r,
    const short* __restrict__ Wp_f, const short* __restrict__ Wp_r,
    const float* __restrict__ b_f,  const float* __restrict__ b_r,
    float* __restrict__ y)
{
    constexpr int HP = 272;
    __shared__ short h_lds[2][16][HP];          // 17.4 KB

    const int tid  = threadIdx.x;
    const int w    = tid >> 6;
    const int lane = tid & 63;
    const int quad = lane >> 4;
    const int l15  = lane & 15;

    const int bx    = blockIdx.x;
    const int dir   = bx >> 7;                  // 0 fwd, 1 rev
    const int rest  = bx & 127;
    const int n_seq = rest >> 2;                // 0..31
    const int bq    = rest & 3;                 // batch quarter (16 each)

    const float* __restrict__ xWP = dir ? xWP_r : xWP_f;
    const short* __restrict__ Wp  = dir ? Wp_r  : Wp_f;
    const float* __restrict__ bb  = dir ? b_r   : b_f;

    float bias[8];
    #pragma unroll
    for (int g = 0; g < 4; ++g)
        #pragma unroll
        for (int q = 0; q < 2; ++q)
            bias[g * 2 + q] = bb[g * 256 + w * 32 + q * 16 + l15];

    const short* wbase = Wp + (size_t)w * 8 * 8 * 512 + lane * 8;

    float c[8];
    #pragma unroll
    for (int i = 0; i < 8; ++i) c[i] = 0.f;

    const int nsteps = dir ? (kN - n_seq) : (n_seq + 1);
    const int t0     = dir ? (kN - 1) : 0;

    // initial prefetch of packed xW + mask for t0
    f32x4 xwn[8];
    f32x4 mkn;
    {
        const f32x4* xb4 = (const f32x4*)xWP
            + ((size_t)(t0 * 4 + bq) * 4096 + w * 512 + lane);
        #pragma unroll
        for (int tau = 0; tau < 8; ++tau) xwn[tau] = xb4[tau * 64];
        mkn = ((const f32x4*)mask_t)[(n_seq * 32 + t0) * 16 + bq * 4 + quad];
    }

    int cur = 0;
    for (int it = 0; it < nsteps; ++it) {
        const int t = dir ? (kN - 1 - it) : it;

        // consume prefetched xW/mask into acc
        f32x4 acc[8];
        #pragma unroll
        for (int tau = 0; tau < 8; ++tau)
            #pragma unroll
            for (int r = 0; r < 4; ++r)
                acc[tau][r] = fmaf(mkn[r], xwn[tau][r], bias[tau]);

        // prefetch next step's xW/mask (overlaps K-loop + epilogue + barrier)
        {
            const int tn = (it + 1 < nsteps) ? (dir ? t - 1 : t + 1) : t;
            const f32x4* xb4 = (const f32x4*)xWP
                + ((size_t)(tn * 4 + bq) * 4096 + w * 512 + lane);
            #pragma unroll
            for (int tau = 0; tau < 8; ++tau) xwn[tau] = xb4[tau * 64];
            mkn = ((const f32x4*)mask_t)[(n_seq * 32 + tn) * 16 + bq * 4 + quad];
        }

        // K loop: h from LDS, W streamed from packed L2-resident layout
        if (it > 0) {
            #pragma unroll
            for (int kt = 0; kt < 8; ++kt) {
                const bf16x8 a = *(const bf16x8*)&h_lds[cur][l15][kt * 32 + quad * 8];
                #pragma unroll
                for (int tau = 0; tau < 8; ++tau) {
                    const bf16x8 bfr = *(const bf16x8*)(wbase + (kt * 8 + tau) * 512);
                    acc[tau] = __builtin_amdgcn_mfma_f32_16x16x32_bf16(
                        a, bfr, acc[tau], 0, 0, 0);
                }
            }
        }

        // epilogue: lane owns units u = w*32+q*16+l15, rows m = quad*4+r
        const int nxt = cur ^ 1;
        #pragma unroll
        for (int q = 0; q < 2; ++q)
            #pragma unroll
            for (int r = 0; r < 4; ++r) {
                const int ci = q * 4 + r;
                const float gI = acc[0 + q][r];
                const float gF = acc[2 + q][r];
                const float gG = acc[4 + q][r];
                const float gO = acc[6 + q][r];
                const float ct = sigm(gF) * c[ci] + sigm(gI) * tanh_f(gG);
                c[ci] = ct;
                const float hn = sigm(gO) * tanh_f(ct);
                const int m = quad * 4 + r;
                const int u = w * 32 + q * 16 + l15;
                h_lds[nxt][m][u] = f2bf(hn);
                if (it == nsteps - 1)
                    y[((size_t)(bq * 16 + m) * kN + n_seq) * (2 * kH)
                      + dir * kH + u] = hn;
            }
        if (it + 1 < nsteps) __syncthreads();
        cur = nxt;
    }
}

// ---------------------------------------------------------------------------
// k3: out = relu(y @ W_fc.T + b_fc). 128 blocks x 16 rows; 128 thr;
// 4x4 register tile; W coalesced float4 from WfcT.
// ---------------------------------------------------------------------------
__global__ __launch_bounds__(128) void k3_out(
    const float* __restrict__ y, const float* __restrict__ WfcT,
    const float* __restrict__ b_fc, float* __restrict__ out)
{
    __shared__ float ys[16][512];               // 32 KB
    const int tid = threadIdx.x;
    const int r0  = blockIdx.x * 16;
    for (int i = tid; i < 2048; i += 128)
        ((f32x4*)ys)[i] = ((const f32x4*)(y + (size_t)r0 * 512))[i];
    __syncthreads();

    const int rowg = tid >> 5;                  // 0..3 -> rows rowg*4..+3
    const int cg   = tid & 31;                  // cols cg*4..+3

    f32x4 acc[4];
    #pragma unroll
    for (int r = 0; r < 4; ++r) acc[r] = (f32x4){0.f, 0.f, 0.f, 0.f};

    #pragma unroll 4
    for (int k = 0; k < 512; ++k) {
        const f32x4 wv = *(const f32x4*)&WfcT[(size_t)k * 128 + cg * 4];
        #pragma unroll
        for (int r = 0; r < 4; ++r) {
            const float yv = ys[rowg * 4 + r][k];
            #pragma unroll
            for (int j = 0; j < 4; ++j)
                acc[r][j] = fmaf(yv, wv[j], acc[r][j]);
        }
    }

    const f32x4 bv = *(const f32x4*)&b_fc[cg * 4];
    #pragma unroll
    for (int r = 0; r < 4; ++r) {
        f32x4 o;
        #pragma unroll
        for (int j = 0; j < 4; ++j) o[j] = fmaxf(acc[r][j] + bv[j], 0.f);
        *(f32x4*)&out[(size_t)(r0 + rowg * 4 + r) * 128 + cg * 4] = o;
    }
}

// ---------------------------------------------------------------------------
extern "C" void kernel_launch(void* const* d_in, const int* in_sizes, int n_in,
                              void* d_out, int out_size, void* d_ws, size_t ws_size,
                              hipStream_t stream) {
    const float* x      = (const float*)d_in[0];
    const float* mask   = (const float*)d_in[1];
    const float* W_ih_f = (const float*)d_in[2];
    const float* W_hh_f = (const float*)d_in[3];
    const float* b_f    = (const float*)d_in[4];
    const float* W_ih_r = (const float*)d_in[5];
    const float* W_hh_r = (const float*)d_in[6];
    const float* b_r    = (const float*)d_in[7];
    const float* W_fc   = (const float*)d_in[8];
    const float* b_fc   = (const float*)d_in[9];
    float* out = (float*)d_out;

    float* ws     = (float*)d_ws;
    float* WihT_f = ws;                        // 131072 f
    float* WihT_r = WihT_f + 131072;           // 131072 f
    float* WfcT   = WihT_r + 131072;           // 65536 f
    float* mask_t = WfcT + 65536;              // 65536 f
    float* xWP_f  = mask_t + 65536;            // 2097152 f
    float* xWP_r  = xWP_f + 2097152;           // 2097152 f
    float* yb     = xWP_r + 2097152;           // 1048576 f
    short* Wp_f   = (short*)(yb + 1048576);    // 262144 bf16
    short* Wp_r   = Wp_f + 262144;             // 262144 bf16

    prep_k<<<456, dim3(32, 8), 0, stream>>>(
        W_ih_f, W_ih_r, W_hh_f, W_hh_r, W_fc, mask,
        WihT_f, WihT_r, WfcT, mask_t, Wp_f, Wp_r);

    k1_xw<<<256, 256, 0, stream>>>(x, WihT_f, WihT_r, xWP_f, xWP_r);
    k2_lstm<<<256, 512, 0, stream>>>(mask_t, xWP_f, xWP_r, Wp_f, Wp_r, b_f, b_r, yb);
    k3_out<<<128, 128, 0, stream>>>(yb, WfcT, b_fc, out);
}